// Round 5
// baseline (182.863 us; speedup 1.0000x reference)
//
#include <hip/hip_runtime.h>
#include <math.h>

// Problem constants (from reference setup_inputs)
#define BB 8
#define CC 192
#define HH 128
#define WW 128
#define NV4   (BB * CC * HH * WW / 4)   // 6291456 vf4 outputs
#define NBLK  2048
#define NTHR  (NBLK * 256)              // 524288 threads
#define NIT   (NV4 / NTHR)              // 12 grid-stride iterations (exact)

// Copy-isomorphic mapping: thread t, iter k handles flat vf4 index
// i = k*NTHR + t. Consecutive lanes = consecutive 16B addresses device-wide;
// the whole device is ONE contiguous window sweeping the tensor in 12 steps —
// the exact access shape of the 6.3 TB/s float4-copy microbenchmark, for both
// the load stream (center row) and the store stream. Row neighbors (+-512B)
// are served out of the hot window by L1/L2.

typedef float vf4 __attribute__((ext_vector_type(4)));

__device__ __forceinline__ float col9(float a0, float a1, float a2,
                                      float b0, float b1, float b2,
                                      float c0, float c1, float c2,
                                      float th, const float* kk) {
    float m;
    m = fmaf(th, kk[0], a0);
    m = fmaxf(m, fmaf(th, kk[1], a1));
    m = fmaxf(m, fmaf(th, kk[2], a2));
    m = fmaxf(m, fmaf(th, kk[3], b0));
    m = fmaxf(m, fmaf(th, kk[4], b1));
    m = fmaxf(m, fmaf(th, kk[5], b2));
    m = fmaxf(m, fmaf(th, kk[6], c0));
    m = fmaxf(m, fmaf(th, kk[7], c1));
    m = fmaxf(m, fmaf(th, kk[8], c2));
    return m;
}

__global__ __launch_bounds__(256) void dynmorph_kernel(
    const float* __restrict__ x,      // [B, C, H, W]
    const float* __restrict__ kern,   // [C, 9]
    const float* __restrict__ gw,     // [C]
    const float* __restrict__ gb,     // [C]
    float* __restrict__ out)          // [B, C, H, W]
{
    const int tid  = threadIdx.x;
    const int lane = tid & 63;
    const int wg   = lane & 31;       // position within a 128-float row (== i & 31)

    int i = blockIdx.x * 256 + tid;   // flat vf4 index

#pragma unroll
    for (int k = 0; k < NIT; ++k, i += NTHR) {
        // A wave spans exactly 2 rows of one image (1024B); images are 64
        // waves each, so c is wave-uniform -> force scalar.
        const int c = __builtin_amdgcn_readfirstlane((i >> 12) % CC);
        const int r = (i >> 5) & (HH - 1);          // local row (half-wave uniform)

        float kk[9];
#pragma unroll
        for (int q = 0; q < 9; ++q) kk[q] = kern[c * 9 + q];
        const float gwc = gw[c];
        const float gbc = gb[c];

        const float* p = x + ((size_t)i << 2);      // center-row vf4 (copy stream)
        const vf4 Bv = *(const vf4*)p;
        const vf4 A  = (r > 0)      ? *(const vf4*)(p - WW) : (vf4)(0.0f);
        const vf4 Cv = (r < HH - 1) ? *(const vf4*)(p + WW) : (vf4)(0.0f);

        // Column halos: within each 32-lane row, neighbors via shfl; lane
        // pairs that cross the row boundary (wg==0/31) are masked to the
        // zero W-edge halo anyway.
        const float aL0 = __shfl_up(A.w, 1),  aR0 = __shfl_down(A.x, 1);
        const float bL0 = __shfl_up(Bv.w, 1), bR0 = __shfl_down(Bv.x, 1);
        const float cL0 = __shfl_up(Cv.w, 1), cR0 = __shfl_down(Cv.x, 1);
        const float aL = (wg == 0)  ? 0.0f : aL0;
        const float bL = (wg == 0)  ? 0.0f : bL0;
        const float cL = (wg == 0)  ? 0.0f : cL0;
        const float aR = (wg == 31) ? 0.0f : aR0;
        const float bR = (wg == 31) ? 0.0f : bR0;
        const float cR = (wg == 31) ? 0.0f : cR0;

        const float t0 = __builtin_amdgcn_rcpf(1.0f + __expf(-fmaf(Bv.x, gwc, gbc)));
        const float t1 = __builtin_amdgcn_rcpf(1.0f + __expf(-fmaf(Bv.y, gwc, gbc)));
        const float t2 = __builtin_amdgcn_rcpf(1.0f + __expf(-fmaf(Bv.z, gwc, gbc)));
        const float t3 = __builtin_amdgcn_rcpf(1.0f + __expf(-fmaf(Bv.w, gwc, gbc)));

        vf4 o;
        o.x = col9(aL,   A.x,  A.y,
                   bL,   Bv.x, Bv.y,
                   cL,   Cv.x, Cv.y, t0, kk);
        o.y = col9(A.x,  A.y,  A.z,
                   Bv.x, Bv.y, Bv.z,
                   Cv.x, Cv.y, Cv.z, t1, kk);
        o.z = col9(A.y,  A.z,  A.w,
                   Bv.y, Bv.z, Bv.w,
                   Cv.y, Cv.z, Cv.w, t2, kk);
        o.w = col9(A.z,  A.w,  aR,
                   Bv.z, Bv.w, bR,
                   Cv.z, Cv.w, cR, t3, kk);

        *(vf4*)(out + ((size_t)i << 2)) = o;        // store stream == copy stream
    }
}

extern "C" void kernel_launch(void* const* d_in, const int* in_sizes, int n_in,
                              void* d_out, int out_size, void* d_ws, size_t ws_size,
                              hipStream_t stream) {
    const float* x    = (const float*)d_in[0];
    const float* kern = (const float*)d_in[1];
    const float* gw   = (const float*)d_in[2];
    const float* gb   = (const float*)d_in[3];
    float* out        = (float*)d_out;

    dim3 grid(NBLK);    // 2048 blocks = 8/CU resident (32 waves, full slots)
    dim3 block(256);
    dynmorph_kernel<<<grid, block, 0, stream>>>(x, kern, gw, gb, out);
}

// Round 7
// 175.950 us; speedup vs baseline: 1.0393x; 1.0393x over previous
//
#include <hip/hip_runtime.h>
#include <math.h>

// Problem constants (from reference setup_inputs)
#define BB 8
#define CC 192
#define HH 128
#define WW 128
#define BANDR 16                    // rows per block (band)
#define NBANDS (HH / BANDR)         // 8 bands per image
#define NBLK  (BB * CC * NBANDS)    // 12288 blocks
#define LROWS (BANDR + 2)           // 18 LDS rows (band + top/bottom halo)

// Minimal-vmem-instruction structure: per 8KB of output a block issues
// 8 center loads + 1 halo load + 8 stores = 17 wave64 vf4 insts (pure copy
// = 16). Each input byte transits L1 exactly once (LDS shares rows).
// No loops: block = load -> one barrier -> compute -> store, ~2us lifetime;
// 48 blocks/CU queued keep the device's address window sliding copy-like.

typedef float vf4 __attribute__((ext_vector_type(4)));

__device__ __forceinline__ float col9(float a0, float a1, float a2,
                                      float b0, float b1, float b2,
                                      float c0, float c1, float c2,
                                      float th, const float* kk) {
    float m;
    m = fmaf(th, kk[0], a0);
    m = fmaxf(m, fmaf(th, kk[1], a1));
    m = fmaxf(m, fmaf(th, kk[2], a2));
    m = fmaxf(m, fmaf(th, kk[3], b0));
    m = fmaxf(m, fmaf(th, kk[4], b1));
    m = fmaxf(m, fmaf(th, kk[5], b2));
    m = fmaxf(m, fmaf(th, kk[6], c0));
    m = fmaxf(m, fmaf(th, kk[7], c1));
    m = fmaxf(m, fmaf(th, kk[8], c2));
    return m;
}

__global__ __launch_bounds__(512) void dynmorph_kernel(
    const float* __restrict__ x,      // [B, C, H, W]
    const float* __restrict__ kern,   // [C, 9]
    const float* __restrict__ gw,     // [C]
    const float* __restrict__ gb,     // [C]
    float* __restrict__ out)          // [B, C, H, W]
{
    __shared__ float sm[LROWS * WW];  // 18 x 512B = 9216 B, linear

    const int tid  = threadIdx.x;     // 0..511
    const int wg   = tid & 31;        // column group within row
    const int col  = wg * 4;
    const int lrow = tid >> 5;        // local row 0..15

    const int blk  = blockIdx.x;
    const int bc   = blk >> 3;        // image id = b*C + c (block-uniform)
    const int band = blk & 7;
    const int c    = bc % CC;
    const int r0   = band * BANDR;

    const float* xb = x   + (size_t)bc * (HH * WW);
    float*       ob = out + (size_t)bc * (HH * WW);

    // ---- Issue all global loads up front ----
    const int gr = r0 + lrow;
    const vf4 Bv = *(const vf4*)(xb + gr * WW + col);   // center (copy-exact stream)

    // Halo rows r0-1 / r0+16: one extra wave64 inst (wave 0 only).
    vf4 hv = (vf4)(0.0f);
    int hvalid = 0, hldsr = 0;
    if (tid < 64) {
        const int hrow = (tid < 32) ? (r0 - 1) : (r0 + BANDR);
        const int clmp = hrow < 0 ? 0 : (hrow > HH - 1 ? HH - 1 : hrow);
        hv     = *(const vf4*)(xb + clmp * WW + (tid & 31) * 4);
        hvalid = (hrow >= 0 && hrow < HH);
        hldsr  = (tid < 32) ? 0 : (LROWS - 1);
    }

    // Block-uniform coefficients (scalar loads; latency hidden by vmem)
    float kk[9];
#pragma unroll
    for (int q = 0; q < 9; ++q) kk[q] = kern[c * 9 + q];
    const float gwc = gw[c];
    const float gbc = gb[c];

    // ---- Stage to LDS ----
    *(vf4*)(&sm[(lrow + 1) * WW + col]) = Bv;
    if (tid < 64) {
        if (!hvalid) hv = (vf4)(0.0f);
        *(vf4*)(&sm[hldsr * WW + (tid & 31) * 4]) = hv;
    }
    __syncthreads();

    // ---- Neighbor rows from LDS, column halos via shuffle ----
    const vf4 A  = *(const vf4*)(&sm[lrow * WW + col]);        // row gr-1
    const vf4 Cv = *(const vf4*)(&sm[(lrow + 2) * WW + col]);  // row gr+1

    const float aL0 = __shfl_up(A.w, 1),  aR0 = __shfl_down(A.x, 1);
    const float bL0 = __shfl_up(Bv.w, 1), bR0 = __shfl_down(Bv.x, 1);
    const float cL0 = __shfl_up(Cv.w, 1), cR0 = __shfl_down(Cv.x, 1);
    const float aL = (wg == 0)  ? 0.0f : aL0;
    const float bL = (wg == 0)  ? 0.0f : bL0;
    const float cL = (wg == 0)  ? 0.0f : cL0;
    const float aR = (wg == 31) ? 0.0f : aR0;
    const float bR = (wg == 31) ? 0.0f : bR0;
    const float cR = (wg == 31) ? 0.0f : cR0;

    const float t0 = __builtin_amdgcn_rcpf(1.0f + __expf(-fmaf(Bv.x, gwc, gbc)));
    const float t1 = __builtin_amdgcn_rcpf(1.0f + __expf(-fmaf(Bv.y, gwc, gbc)));
    const float t2 = __builtin_amdgcn_rcpf(1.0f + __expf(-fmaf(Bv.z, gwc, gbc)));
    const float t3 = __builtin_amdgcn_rcpf(1.0f + __expf(-fmaf(Bv.w, gwc, gbc)));

    vf4 o;
    o.x = col9(aL,   A.x,  A.y,
               bL,   Bv.x, Bv.y,
               cL,   Cv.x, Cv.y, t0, kk);
    o.y = col9(A.x,  A.y,  A.z,
               Bv.x, Bv.y, Bv.z,
               Cv.x, Cv.y, Cv.z, t1, kk);
    o.z = col9(A.y,  A.z,  A.w,
               Bv.y, Bv.z, Bv.w,
               Cv.y, Cv.z, Cv.w, t2, kk);
    o.w = col9(A.z,  A.w,  aR,
               Bv.z, Bv.w, bR,
               Cv.z, Cv.w, cR, t3, kk);

    *(vf4*)(ob + gr * WW + col) = o;   // store (copy-exact stream)
}

extern "C" void kernel_launch(void* const* d_in, const int* in_sizes, int n_in,
                              void* d_out, int out_size, void* d_ws, size_t ws_size,
                              hipStream_t stream) {
    const float* x    = (const float*)d_in[0];
    const float* kern = (const float*)d_in[1];
    const float* gw   = (const float*)d_in[2];
    const float* gb   = (const float*)d_in[3];
    float* out        = (float*)d_out;

    dim3 grid(NBLK);     // 12288 short-lived blocks; 48 queued per CU
    dim3 block(512);     // 8 waves; 4 blocks/CU resident (32 wave slots)
    dynmorph_kernel<<<grid, block, 0, stream>>>(x, kern, gw, gb, out);
}